// Round 10
// baseline (216.368 us; speedup 1.0000x reference)
//
#include <hip/hip_runtime.h>
#include <hip/hip_bf16.h>
#include <stdint.h>

typedef __attribute__((ext_vector_type(4))) float f32x4;
typedef __attribute__((ext_vector_type(2))) float f32x2;
typedef __attribute__((ext_vector_type(8))) short short8;
typedef __attribute__((ext_vector_type(4))) unsigned int u32x4;

__device__ __forceinline__ unsigned short f2bf(float x) {
  __hip_bfloat16 h = __float2bfloat16(x);
  union { __hip_bfloat16 b; unsigned short s; } u; u.b = h;
  return u.s;
}
__device__ __forceinline__ unsigned int pkbf(float lo, float hi) {
  return (unsigned int)f2bf(lo) | ((unsigned int)f2bf(hi) << 16);
}
__device__ __forceinline__ f32x4 ld4(const float* p) { return *(const f32x4*)p; }

// out[b] = (adj[b] with zero diagonal) @ means[b]
// adj [32][1024][1024] f32, means [32][1024][128] f32, out [32][1024][128] f32.
//
// R8 structure: B-phase-resident GEMM, barrier-minimal.
//  - grid 512 WGs (32 batches x 16 row-tiles of 64), 256 thr = 4 waves, 2 WG/CU.
//  - LDS 64 KB: 2 x 32 KB buffers; buffer holds one K-phase of B (k-width 128,
//    all 128 cols, bf16 fragment-major: frag(n,s) at (n*4+s)*1024 + lane*16).
//  - 8 phases x 2 inner steps; ONE barrier per phase (8+1 total vs 33 before).
//    Inside a phase there are no barriers: A prefetch + next-phase B staging
//    float across MFMA steps via compiler counted-waitcnt scheduling.

#define MSK(v, k) (((k) == arow) ? 0.f : (v))

#define LOADA(kt, Aq) do {                                               \
    const float* p_ = aP + (kt) * 64;                                    \
    Aq[0] = ld4(p_); Aq[1] = ld4(p_ + 4);                                \
    Aq[2] = ld4(p_ + 32); Aq[3] = ld4(p_ + 36);                          \
  } while (0)

// Stage-load group h of phase q1: 8 f32x2 (cols fc,fc+1; k = q1*128+h*32+g*8+e)
#define STAGE_LOAD(q1, h, S_) do {                                       \
    const float* p_ = bP0 + (q1) * 16384 + (h) * 4096;                   \
    _Pragma("unroll") for (int e_ = 0; e_ < 8; ++e_)                     \
      S_[e_] = *(const f32x2*)(p_ + e_ * 128);                           \
  } while (0)

// Convert + write group h into buffer nb (32 B contiguous per thread)
#define STAGE_WRITE(nb, h, S_) do {                                      \
    u32x4 ua_, ub_;                                                      \
    ua_[0] = pkbf(S_[0].x, S_[1].x); ua_[1] = pkbf(S_[2].x, S_[3].x);    \
    ua_[2] = pkbf(S_[4].x, S_[5].x); ua_[3] = pkbf(S_[6].x, S_[7].x);    \
    ub_[0] = pkbf(S_[0].y, S_[1].y); ub_[1] = pkbf(S_[2].y, S_[3].y);    \
    ub_[2] = pkbf(S_[4].y, S_[5].y); ub_[3] = pkbf(S_[6].y, S_[7].y);    \
    char* p_ = wB + (nb) * 32768 + (h) * 1024;                           \
    *(u32x4*)p_ = ua_; *(u32x4*)(p_ + 16) = ub_;                         \
  } while (0)

// One 64-wide K-step: convert A regs (diag-masked if kt==diag_kt), 16 MFMA.
#define COMPUTE(buf, kt, Aq) do {                                        \
    short8 af0_, af1_;                                                   \
    {                                                                    \
      union { u32x4 q; short8 s; } u0_, u1_;                             \
      if ((kt) == diag_kt) {                                             \
        const int jb_ = (kt) * 64 + kg;                                  \
        u0_.q[0] = pkbf(MSK(Aq[0][0], jb_ + 0),  MSK(Aq[0][1], jb_ + 1)); \
        u0_.q[1] = pkbf(MSK(Aq[0][2], jb_ + 2),  MSK(Aq[0][3], jb_ + 3)); \
        u0_.q[2] = pkbf(MSK(Aq[1][0], jb_ + 4),  MSK(Aq[1][1], jb_ + 5)); \
        u0_.q[3] = pkbf(MSK(Aq[1][2], jb_ + 6),  MSK(Aq[1][3], jb_ + 7)); \
        u1_.q[0] = pkbf(MSK(Aq[2][0], jb_ + 32), MSK(Aq[2][1], jb_ + 33)); \
        u1_.q[1] = pkbf(MSK(Aq[2][2], jb_ + 34), MSK(Aq[2][3], jb_ + 35)); \
        u1_.q[2] = pkbf(MSK(Aq[3][0], jb_ + 36), MSK(Aq[3][1], jb_ + 37)); \
        u1_.q[3] = pkbf(MSK(Aq[3][2], jb_ + 38), MSK(Aq[3][3], jb_ + 39)); \
      } else {                                                           \
        u0_.q[0] = pkbf(Aq[0][0], Aq[0][1]); u0_.q[1] = pkbf(Aq[0][2], Aq[0][3]); \
        u0_.q[2] = pkbf(Aq[1][0], Aq[1][1]); u0_.q[3] = pkbf(Aq[1][2], Aq[1][3]); \
        u1_.q[0] = pkbf(Aq[2][0], Aq[2][1]); u1_.q[1] = pkbf(Aq[2][2], Aq[2][3]); \
        u1_.q[2] = pkbf(Aq[3][0], Aq[3][1]); u1_.q[3] = pkbf(Aq[3][2], Aq[3][3]); \
      }                                                                  \
      af0_ = u0_.s; af1_ = u1_.s;                                        \
    }                                                                    \
    const char* base_ = rP + (buf) * 32768;                              \
    const int c_ = (kt) & 1;                                             \
    _Pragma("unroll")                                                    \
    for (int n_ = 0; n_ < 8; ++n_) {                                     \
      short8 bf0_ = *(const short8*)(base_ + (n_ * 4 + 2 * c_ + 0) * 1024); \
      acc[n_] = __builtin_amdgcn_mfma_f32_16x16x32_bf16(af0_, bf0_, acc[n_], 0, 0, 0); \
      short8 bf1_ = *(const short8*)(base_ + (n_ * 4 + 2 * c_ + 1) * 1024); \
      acc[n_] = __builtin_amdgcn_mfma_f32_16x16x32_bf16(af1_, bf1_, acc[n_], 0, 0, 0); \
    }                                                                    \
  } while (0)

__global__ __launch_bounds__(256, 2) void gcn_kernel(
    const float* __restrict__ means, const float* __restrict__ adj,
    float* __restrict__ out) {
  __shared__ char ldsB[65536];  // 2 x 32 KB B-phase buffers

  const int tid = (int)threadIdx.x;
  const int l = tid & 63;
  const int w = tid >> 6;  // wave 0..3
  const int bid = (int)blockIdx.x;
  // bid = xcd(3b) | rtile(4b) | bb(2b): same-batch WGs share an XCD L2.
  const int batch = (bid & 7) * 4 + (bid >> 7);
  const int rtile = (bid >> 3) & 15;
  const int rbase = rtile * 64;

  const float* aB = adj + (size_t)batch * 1048576;
  const float* mB = means + (size_t)batch * 131072;
  float* oB = out + (size_t)batch * 131072;

  // A-fragment: lane l -> row l&15 (of wave's 16), k-group (l>>4)*8
  const int arow = rbase + w * 16 + (l & 15);
  const int kg = (l >> 4) * 8;
  const float* aP = aB + (size_t)arow * 1024 + kg;
  const int diag_kt = arow >> 6;  // wave-uniform

  // B staging decode: t = n(3b)|g(2b)|fc(3b); each thread stages 4 groups/phase
  const int n_t = tid >> 5;
  const int g_t = (tid >> 3) & 3;
  const int fc_t = (tid & 7) * 2;
  const float* bP0 = mB + (size_t)(g_t * 8) * 128 + n_t * 16 + fc_t;
  char* wB = ldsB + n_t * 4096 + g_t * 256 + fc_t * 16;  // + nb*32768 + h*1024
  const char* rP = ldsB + l * 16;

  f32x4 acc[8];
#pragma unroll
  for (int n = 0; n < 8; ++n) { f32x4 z = {0.f, 0.f, 0.f, 0.f}; acc[n] = z; }

  f32x4 Ar[2][4];  // A double-buffer; all indices compile-time post-unroll

  // Prologue: stage phase 0 into buf 0, prefetch A(kt=0)
  {
    f32x2 S0[8], S1[8], S2[8], S3[8];
    STAGE_LOAD(0, 0, S0); STAGE_LOAD(0, 1, S1);
    STAGE_LOAD(0, 2, S2); STAGE_LOAD(0, 3, S3);
    LOADA(0, Ar[0]);
    STAGE_WRITE(0, 0, S0); STAGE_WRITE(0, 1, S1);
    STAGE_WRITE(0, 2, S2); STAGE_WRITE(0, 3, S3);
  }
  __syncthreads();

#pragma unroll
  for (int kt = 0; kt < 16; ++kt) {
    const int q = kt >> 1;       // phase 0..7
    const int c = kt & 1;        // inner step
    const int buf = q & 1;
    const int nbuf = buf ^ 1;
    const int cur = kt & 1;      // A reg bank
    const int nxt = cur ^ 1;

    if (kt < 15) LOADA(kt + 1, Ar[nxt]);

    f32x2 S0[8], S1[8];
    if (q < 7) {  // stage groups (2c, 2c+1) of phase q+1
      STAGE_LOAD(q + 1, 2 * c + 0, S0);
      STAGE_LOAD(q + 1, 2 * c + 1, S1);
    }

    COMPUTE(buf, kt, Ar[cur]);

    if (q < 7) {
      STAGE_WRITE(nbuf, 2 * c + 0, S0);
      STAGE_WRITE(nbuf, 2 * c + 1, S1);
    }
    if (c == 1) __syncthreads();  // end of phase: 8 barriers total
  }

  // Epilogue: C/D col = l&15, row = (l>>4)*4 + j
  const int orow = rbase + w * 16 + (l >> 4) * 4;
  const int ocol = l & 15;
  float* op = oB + (size_t)orow * 128 + ocol;
#pragma unroll
  for (int n = 0; n < 8; ++n)
#pragma unroll
    for (int j = 0; j < 4; ++j)
      op[j * 128 + n * 16] = acc[n][j];
}

extern "C" void kernel_launch(void* const* d_in, const int* in_sizes, int n_in,
                              void* d_out, int out_size, void* d_ws, size_t ws_size,
                              hipStream_t stream) {
  const float* means = (const float*)d_in[0];  // regional_means (32,1024,128)
  const float* adj = (const float*)d_in[1];    // adj (32,1024,1024)
  float* out = (float*)d_out;                  // (32,1024,128) f32
  hipLaunchKernelGGL(gcn_kernel, dim3(512), dim3(256), 0, stream, means, adj, out);
}